// Round 13
// baseline (240.469 us; speedup 1.0000x reference)
//
#include <hip/hip_runtime.h>

typedef __bf16 bf16;
typedef __bf16 bf16x4 __attribute__((ext_vector_type(4)));
typedef __bf16 bf16x8 __attribute__((ext_vector_type(8)));
typedef float floatx4 __attribute__((ext_vector_type(4)));

#define GLOAD_LDS16(gp, lp) \
  __builtin_amdgcn_global_load_lds( \
      (const __attribute__((address_space(1))) void*)(gp), \
      (__attribute__((address_space(3))) void*)(lp), 16, 0, 0)

// ---------------- QKV GEMM with FUSED fp32->bf16 conversion (cvt kernel deleted) ----------------
// C = A @ B^T + bias; A,B raw fp32. Staging is reg-staged with the T14 split:
// global float4 loads issued right after the barrier (in flight during the
// compute phase), scalar-cast to bf16 + one ds_write_b128 per chunk after
// compute. LDS layout stays bf16-LINEAR and identical to the proven
// global_load_lds path (dest = chunk*512 + lane*8 elems), so frag reads and
// epilogues are byte-identical to R11's verified kernel. Unlike R5's failed
// fusion, conversion is on the STAGING path, not the MFMA critical path.
// MODE 0: bf16 out per-head [N,H,S,64] (Q,K). MODE 1: transposed [N,H,64,S] (V).
template <int MODE>
__device__ __forceinline__ void gemm_body(
    const float* __restrict__ A, const float* __restrict__ B,
    const float* __restrict__ bias, bf16* __restrict__ Cout,
    int bx, int by, bf16* __restrict__ SMEM) {
  constexpr int K = 1024;
  constexpr int NSTEP = K / 32;  // 32
  const int tid = threadIdx.x;
  const int lane = tid & 63;
  const int wave = tid >> 6;
  const int quad = lane >> 4;
  const int l16 = lane & 15;
  const int wm = (wave >> 1) * 64;
  const int wn = (wave & 1) * 64;
  const int am0 = by * 128;
  const int bn0 = bx * 128;
  const int srow = lane >> 2;        // 0..15
  const int scol = (lane & 3) * 8;   // 0/8/16/24 elems

  floatx4 acc[4][4] = {};
  float4 ra[2][2], rb[2][2];  // in-flight fp32 chunks (A,B x 2 chunks x 8 floats)

  auto loadRegs = [&](int step) {
    const int k0 = step * 32;
#pragma unroll
    for (int j = 0; j < 2; j++) {
      const int row = (wave * 2 + j) * 16 + srow;
      const float* pa = A + (size_t)(am0 + row) * K + k0 + scol;
      ra[j][0] = *reinterpret_cast<const float4*>(pa);
      ra[j][1] = *reinterpret_cast<const float4*>(pa + 4);
      const float* pb = B + (size_t)(bn0 + row) * K + k0 + scol;
      rb[j][0] = *reinterpret_cast<const float4*>(pb);
      rb[j][1] = *reinterpret_cast<const float4*>(pb + 4);
    }
  };

  auto cvtWrite = [&](int bufsel) {
    bf16* As = SMEM + bufsel * 8192;
    bf16* Bs = As + 4096;
#pragma unroll
    for (int j = 0; j < 2; j++) {
      const int off = (wave * 2 + j) * 512 + lane * 8;  // == gload_lds linear dest
      bf16x8 va = {(bf16)ra[j][0].x, (bf16)ra[j][0].y, (bf16)ra[j][0].z, (bf16)ra[j][0].w,
                   (bf16)ra[j][1].x, (bf16)ra[j][1].y, (bf16)ra[j][1].z, (bf16)ra[j][1].w};
      bf16x8 vb = {(bf16)rb[j][0].x, (bf16)rb[j][0].y, (bf16)rb[j][0].z, (bf16)rb[j][0].w,
                   (bf16)rb[j][1].x, (bf16)rb[j][1].y, (bf16)rb[j][1].z, (bf16)rb[j][1].w};
      *reinterpret_cast<bf16x8*>(As + off) = va;
      *reinterpret_cast<bf16x8*>(Bs + off) = vb;
    }
  };

  auto compute = [&](int bufsel) {
    const bf16* As = SMEM + bufsel * 8192;
    const bf16* Bs = As + 4096;
    bf16x8 af[4], bfv[4];
#pragma unroll
    for (int mi = 0; mi < 4; mi++)
      af[mi] = *reinterpret_cast<const bf16x8*>(&As[(wm + mi * 16 + l16) * 32 + quad * 8]);
#pragma unroll
    for (int ni = 0; ni < 4; ni++)
      bfv[ni] = *reinterpret_cast<const bf16x8*>(&Bs[(wn + ni * 16 + l16) * 32 + quad * 8]);
#pragma unroll
    for (int mi = 0; mi < 4; mi++)
#pragma unroll
      for (int ni = 0; ni < 4; ni++)
        acc[mi][ni] = __builtin_amdgcn_mfma_f32_16x16x32_bf16(af[mi], bfv[ni], acc[mi][ni], 0, 0, 0);
  };

  // prologue: tile 0 loaded, converted, written to buf0
  loadRegs(0);
  cvtWrite(0);
  for (int t = 0; t < NSTEP; t += 2) {
    // barrier: lgkm drain makes the just-written buf visible; all waves past
    // compute of the other buf -> safe to overwrite it this iteration.
    __syncthreads();
    loadRegs(t + 1);            // fp32 loads in flight during compute(0)
    compute(0);                 // step t   -> buf0
    cvtWrite(1);                // drain loads (compiler vmcnt), write buf1
    __syncthreads();
    if (t + 2 < NSTEP) loadRegs(t + 2);
    compute(1);                 // step t+1 -> buf1
    if (t + 2 < NSTEP) cvtWrite(0);
  }

  // LDS-bounce epilogue: wave-private 4 KB region, XOR-chunk swizzle,
  // coalesced 16B global stores.  [C/D layout col=lane&15, row=quad*4+reg, m89]
  __syncthreads();
  bf16* T = SMEM + wave * 2048;
  const int nb = (am0 + wm) >> 11;
  const int sq0 = (am0 + wm) & 2047;
  const int h = (bn0 + wn) >> 6;
  const int nh = nb * 16 + h;
  const int r8 = lane >> 3, c8 = lane & 7;

  if constexpr (MODE == 0) {
#pragma unroll
    for (int pp = 0; pp < 2; pp++) {
#pragma unroll
      for (int mm = 0; mm < 2; mm++) {
        const int mi = pp * 2 + mm;
#pragma unroll
        for (int ni = 0; ni < 4; ni++) {
          const int d = ni * 16 + l16;
          const float bc = bias[bn0 + wn + d];
#pragma unroll
          for (int r = 0; r < 4; r++) {
            const int s = mm * 16 + quad * 4 + r;
            T[s * 64 + (d & 7) + 8 * ((d >> 3) ^ (s & 7))] = (bf16)(acc[mi][ni][r] + bc);
          }
        }
      }
#pragma unroll
      for (int it = 0; it < 4; it++) {
        const int s = it * 8 + r8;
        bf16x8 vv = *reinterpret_cast<const bf16x8*>(&T[s * 64 + ((c8 ^ r8) * 8)]);
        *reinterpret_cast<bf16x8*>(
            Cout + ((size_t)nh * 2048 + sq0 + pp * 32 + s) * 64 + c8 * 8) = vv;
      }
    }
  } else {  // MODE == 1
#pragma unroll
    for (int pp = 0; pp < 2; pp++) {
#pragma unroll
      for (int nn = 0; nn < 2; nn++) {
        const int ni = pp * 2 + nn;
        const int dp = nn * 16 + l16;
        const float bc = bias[bn0 + wn + pp * 32 + dp];
#pragma unroll
        for (int mi = 0; mi < 4; mi++) {
#pragma unroll
          for (int r = 0; r < 4; r++) {
            const int s = mi * 16 + quad * 4 + r;
            T[dp * 64 + (s & 7) + 8 * ((s >> 3) ^ (dp & 7))] = (bf16)(acc[mi][ni][r] + bc);
          }
        }
      }
#pragma unroll
      for (int it = 0; it < 4; it++) {
        const int dp = it * 8 + r8;
        bf16x8 vv = *reinterpret_cast<const bf16x8*>(&T[dp * 64 + ((c8 ^ r8) * 8)]);
        *reinterpret_cast<bf16x8*>(
            Cout + ((size_t)nh * 64 + pp * 32 + dp) * 2048 + sq0 + c8 * 8) = vv;
      }
    }
  }
}

// QKV: T1 XCD-contiguous remap (R3-verified). 768 blocks = 8*96, bijective.
__global__ __launch_bounds__(256) void gemm_qkv(
    const float* __restrict__ A0, const float* __restrict__ B0, const float* __restrict__ c0, bf16* __restrict__ C0,
    const float* __restrict__ A1, const float* __restrict__ B1, const float* __restrict__ c1, bf16* __restrict__ C1,
    const float* __restrict__ A2, const float* __restrict__ B2, const float* __restrict__ c2, bf16* __restrict__ C2) {
  extern __shared__ __align__(16) bf16 SMEM[];  // 32 KB dynamic
  const int lin = blockIdx.x + (blockIdx.y << 3) + (blockIdx.z << 8);  // 0..767
  const int swz = (lin & 7) * 96 + (lin >> 3);                          // bijective
  const int bz = swz >> 8;
  const int by = (swz >> 3) & 31;
  const int bx = swz & 7;
  if (bz == 0)      gemm_body<0>(A0, B0, c0, C0, bx, by, SMEM);   // Q
  else if (bz == 1) gemm_body<0>(A1, B1, c1, C1, bx, by, SMEM);   // K
  else              gemm_body<1>(A2, B2, c2, C2, bx, by, SMEM);   // V^T
}

// ---------------- final projection: 128x64 tiles, 512 blocks = 2/CU (R11-verified) ----------------
// A = ao (bf16) via global_load_lds; B = Wo raw fp32, reg-staged + converted.
__global__ __launch_bounds__(256) void gemm_out(
    const bf16* __restrict__ A, const float* __restrict__ B,
    const float* __restrict__ bias, float* __restrict__ C) {
  extern __shared__ __align__(16) bf16 SMEM[];  // 24 KB dynamic
  constexpr int K = 1024, N = 1024;
  constexpr int NSTEP = 32;
  const int lin = blockIdx.x + (blockIdx.y << 4);  // x:0..15, y:0..31
  const int swz = (lin & 7) * 64 + (lin >> 3);     // bijective: 512 = 8*64
  const int by = swz >> 4;        // 0..31
  const int bx = swz & 15;        // 0..15
  const int tid = threadIdx.x;
  const int lane = tid & 63;
  const int wave = tid >> 6;
  const int quad = lane >> 4;
  const int l16 = lane & 15;
  const int wm = (wave >> 1) * 64;   // 0 / 64
  const int wn = (wave & 1) * 32;    // 0 / 32
  const int am0 = by * 128;
  const int bn0 = bx * 64;
  const int srow = lane >> 2;
  const int scol = (lane & 3) * 8;

  floatx4 acc[4][2] = {};
  float4 rb[2];

  auto stageA = [&](int step, int bufsel) {
    const int k0 = step * 32;
    bf16* As = SMEM + bufsel * 6144;
#pragma unroll
    for (int j = 0; j < 2; j++) {  // A: chunks 2w, 2w+1
      const int chunk = wave * 2 + j;
      const int row = chunk * 16 + srow;
      GLOAD_LDS16(A + (size_t)(am0 + row) * K + k0 + scol, As + chunk * 512);
    }
  };
  auto loadB = [&](int step) {
    const int k0 = step * 32;
    const float* pb = B + (size_t)(bn0 + wave * 16 + srow) * K + k0 + scol;
    rb[0] = *reinterpret_cast<const float4*>(pb);
    rb[1] = *reinterpret_cast<const float4*>(pb + 4);
  };
  auto cvtWriteB = [&](int bufsel) {
    bf16* Bs = SMEM + bufsel * 6144 + 4096;
    bf16x8 vb = {(bf16)rb[0].x, (bf16)rb[0].y, (bf16)rb[0].z, (bf16)rb[0].w,
                 (bf16)rb[1].x, (bf16)rb[1].y, (bf16)rb[1].z, (bf16)rb[1].w};
    *reinterpret_cast<bf16x8*>(Bs + wave * 512 + lane * 8) = vb;
  };

  auto compute = [&](int bufsel) {
    const bf16* As = SMEM + bufsel * 6144;
    const bf16* Bs = As + 4096;
    bf16x8 af[4], bfv[2];
#pragma unroll
    for (int mi = 0; mi < 4; mi++)
      af[mi] = *reinterpret_cast<const bf16x8*>(&As[(wm + mi * 16 + l16) * 32 + quad * 8]);
#pragma unroll
    for (int ni = 0; ni < 2; ni++)
      bfv[ni] = *reinterpret_cast<const bf16x8*>(&Bs[(wn + ni * 16 + l16) * 32 + quad * 8]);
#pragma unroll
    for (int mi = 0; mi < 4; mi++)
#pragma unroll
      for (int ni = 0; ni < 2; ni++)
        acc[mi][ni] = __builtin_amdgcn_mfma_f32_16x16x32_bf16(af[mi], bfv[ni], acc[mi][ni], 0, 0, 0);
  };

  stageA(0, 0); loadB(0); cvtWriteB(0);
  for (int t = 0; t < NSTEP; t += 2) {
    __syncthreads();
    stageA(t + 1, 1); loadB(t + 1);
    compute(0);
    cvtWriteB(1);
    __syncthreads();
    if (t + 2 < NSTEP) { stageA(t + 2, 0); loadB(t + 2); }
    compute(1);
    if (t + 2 < NSTEP) cvtWriteB(0);
  }

  // direct fp32 epilogue [m89 C/D layout]
#pragma unroll
  for (int mi = 0; mi < 4; mi++) {
#pragma unroll
    for (int ni = 0; ni < 2; ni++) {
      const int col = bn0 + wn + ni * 16 + l16;
      const float bb = bias[col];
      const int row = am0 + wm + mi * 16 + quad * 4;
#pragma unroll
      for (int r = 0; r < 4; r++)
        C[(size_t)(row + r) * N + col] = acc[mi][ni][r] + bb;
    }
  }
}

// ---------------- causal flash attention: split-K + zero-shuffle PV ----------------
// Zero-shuffle PV (R7/R8-verified): sigma(quad,j)=kc*32+(j>>2)*16+quad*4+(j&3)
// applied to both PV operands makes the A-operand the lane's own P registers
// (union-aliased, zero packing movs). Combine stays a SEPARATE dispatch:
// R10 proved the fused handshake costs ~40 us (device-scope threadfence forces
// per-XCD L2 writeback; partials cross XCDs at HBM-miss latency inline).
#define S_LEN 2048
#define EMB 1024
#define QT 128
#define KTILE 64
#define SCALE2 (0.03125f * 1.44269504f)

__global__ __launch_bounds__(256) void attn_kernel(
    const bf16* __restrict__ Qh, const bf16* __restrict__ Kh,
    const bf16* __restrict__ Vt, bf16* __restrict__ O,
    float* __restrict__ Opart, float* __restrict__ lpart) {
  __shared__ __align__(16) bf16 Ks[2 * KTILE * 64];  // 2 x 8 KB, swizzled cols
  __shared__ __align__(16) bf16 Vs[2 * 64 * KTILE];  // 2 x 8 KB, swizzled cols

  const int tid = threadIdx.x;
  const int lane = tid & 63;
  const int wave = tid >> 6;
  const int quad = lane >> 4;
  const int l16 = lane & 15;
  const int wq = wave * 32;

  const int c = blockIdx.x;       // 0..255
  const int role = blockIdx.y;    // 0..2
  const int nh = c >> 3;
  const int t = c & 7;
  const int n = nh >> 4;
  const int h = nh & 15;
  int qt, kt0, kt1;
  if (role == 0) { qt = t; kt0 = 0; kt1 = 2 * t + 2; }
  else {
    qt = 15 - t;
    const int halfk = qt + 1;
    kt0 = (role == 1) ? 0 : halfk;
    kt1 = (role == 1) ? halfk : 2 * halfk;
  }
  const int q0 = qt * QT;

  // Q B-frags in registers
  bf16x8 aq[2][2];
  {
    const bf16* Qb = Qh + ((size_t)nh * S_LEN + q0 + wq + l16) * 64 + quad * 8;
#pragma unroll
    for (int mi = 0; mi < 2; mi++)
#pragma unroll
      for (int kc = 0; kc < 2; kc++)
        aq[mi][kc] = *reinterpret_cast<const bf16x8*>(Qb + mi * 16 * 64 + kc * 32);
  }

  float l_part[2] = {};
  floatx4 o_acc[2][4] = {};

  const bf16* Kbase = Kh + (size_t)nh * S_LEN * 64;
  const bf16* Vbase = Vt + (size_t)nh * 64 * S_LEN;

  const int srl = lane >> 3;
  const int sc8 = lane & 7;

  auto stage = [&](int kt) {
    const int k0s = kt * KTILE;
    const int buf = (kt & 1) * 4096;
#pragma unroll
    for (int j = 0; j < 2; j++) {
      const int rl = wave * 16 + j * 8 + srl;
      const int c8s = ((sc8 ^ (rl & 7)) * 8);
      GLOAD_LDS16(Kbase + (size_t)(k0s + rl) * 64 + c8s, Ks + buf + (wave * 16 + j * 8) * 64);
      GLOAD_LDS16(Vbase + (size_t)rl * S_LEN + k0s + c8s, Vs + buf + (wave * 16 + j * 8) * 64);
    }
  };

  stage(kt0);
  for (int kt = kt0; kt < kt1; kt++) {
    const int k0 = kt * KTILE;
    __syncthreads();                  // drains cur-tile staging / buf reuse
    if (kt + 1 < kt1) stage(kt + 1);  // in flight during this tile's compute
    const bf16* Kc = Ks + (kt & 1) * 4096;
    const bf16* Vc = Vs + (kt & 1) * 4096;

    // S^T = K Q^T : col=l16=q, row=quad*4+r=k-pos [m89 layout]
    floatx4 s_acc[2][4] = {};
#pragma unroll
    for (int kc = 0; kc < 2; kc++) {
      bf16x8 bk[4];
#pragma unroll
      for (int ni = 0; ni < 4; ni++)
        bk[ni] = *reinterpret_cast<const bf16x8*>(
            &Kc[(ni * 16 + l16) * 64 + (((kc * 4 + quad) ^ (l16 & 7)) * 8)]);
#pragma unroll
      for (int mi = 0; mi < 2; mi++)
#pragma unroll
        for (int ni = 0; ni < 4; ni++)
          s_acc[mi][ni] = __builtin_amdgcn_mfma_f32_16x16x32_bf16(bk[ni], aq[mi][kc], s_acc[mi][ni], 0, 0, 0);
    }

    // max-free exp2 softmax; P in registers; union q[ni]-writes / w[kc]-reads
    const bool needMask = (k0 + KTILE - 1) > (q0 + wq);  // wave-uniform
    const int qg = q0 + wq + l16;
    union PU { bf16x8 w[2]; bf16x4 q[4]; };
    PU P[2];
#pragma unroll
    for (int mi = 0; mi < 2; mi++) {
#pragma unroll
      for (int ni = 0; ni < 4; ni++) {
        const int kgb = k0 + ni * 16 + quad * 4;
        bf16x4 pk;
#pragma unroll
        for (int r = 0; r < 4; r++) {
          float pr = __builtin_amdgcn_exp2f(s_acc[mi][ni][r] * SCALE2);
          if (needMask) pr = ((kgb + r) <= (qg + mi * 16)) ? pr : 0.f;
          l_part[mi] += pr;
          pk[r] = (bf16)pr;
        }
        P[mi].q[ni] = pk;
      }
    }

    // O += P @ V, k-slot bijection sigma: A-operand = P[mi].w[kc]
#pragma unroll
    for (int kc = 0; kc < 2; kc++) {
      bf16x8 bv[4];
#pragma unroll
      for (int di = 0; di < 4; di++) {
        const bf16* base = Vc + (di * 16 + l16) * 64;
        const int e = l16 & 7;
        union VU { bf16x8 v8; bf16x4 h[2]; } vu;
        vu.h[0] = *reinterpret_cast<const bf16x4*>(
            base + (((kc * 4 + (quad >> 1)) ^ e) * 8) + (quad & 1) * 4);
        vu.h[1] = *reinterpret_cast<const bf16x4*>(
            base + (((kc * 4 + 2 + (quad >> 1)) ^ e) * 8) + (quad & 1) * 4);
        bv[di] = vu.v8;
      }
#pragma unroll
      for (int mi = 0; mi < 2; mi++)
#pragma unroll
        for (int di = 0; di < 4; di++)
          o_acc[mi][di] = __builtin_amdgcn_mfma_f32_16x16x32_bf16(P[mi].w[kc], bv[di], o_acc[mi][di], 0, 0, 0);
    }
  }

  // l reduction: sum across the 4 quads (lanes sharing l16)
  float l_sum[2];
#pragma unroll
  for (int mi = 0; mi < 2; mi++) {
    float s = l_part[mi];
    s += __shfl_xor(s, 16);
    s += __shfl_xor(s, 32);
    l_sum[mi] = s;
  }

  if (role == 0) {
    bf16* Op = O + ((size_t)(n * S_LEN + q0 + wq)) * EMB + h * 64;
#pragma unroll
    for (int mi = 0; mi < 2; mi++) {
      const float linv = 1.0f / l_sum[mi];
#pragma unroll
      for (int r = 0; r < 4; r++) {
        const float inv = __shfl(linv, quad * 4 + r);
        bf16* orow = Op + (size_t)(mi * 16 + quad * 4 + r) * EMB;
#pragma unroll
        for (int di = 0; di < 4; di++)
          orow[di * 16 + l16] = (bf16)(o_acc[mi][di][r] * inv);
      }
    }
  } else {
    // half chunk: store fp32 partials (slot = c, chunk = role-1)
    float* Ob = Opart + ((size_t)c * 2 + (role - 1)) * (QT * 64);
    float* lb = lpart + ((size_t)c * 2 + (role - 1)) * QT;
#pragma unroll
    for (int mi = 0; mi < 2; mi++)
      if (lane < 16) lb[wq + mi * 16 + lane] = l_sum[mi];
#pragma unroll
    for (int mi = 0; mi < 2; mi++)
#pragma unroll
      for (int r = 0; r < 4; r++) {
        float* orow = Ob + (size_t)(wq + mi * 16 + quad * 4 + r) * 64;
#pragma unroll
        for (int di = 0; di < 4; di++)
          orow[di * 16 + l16] = o_acc[mi][di][r];
      }
  }
}

// ---------------- combine: O = (O1+O2)/(l1+l2) for qt = 8..15 ----------------
__global__ __launch_bounds__(256) void attn_combine(
    const float* __restrict__ Opart, const float* __restrict__ lpart,
    bf16* __restrict__ O) {
  const int c = blockIdx.x;            // 0..255
  const int nh = c >> 3;
  const int t = c & 7;
  const int qt = 15 - t;
  const int n = nh >> 4;
  const int h = nh & 15;
  const float* O1 = Opart + (size_t)c * 2 * (QT * 64);
  const float* O2 = O1 + QT * 64;
  const float* l1 = lpart + (size_t)c * 2 * QT;
  const float* l2 = l1 + QT;
  const int tid = threadIdx.x;
  for (int i = tid; i < QT * 64 / 4; i += 256) {  // float4 granularity
    const int row = i >> 4;
    const float inv = 1.0f / (l1[row] + l2[row]);
    float4 a = reinterpret_cast<const float4*>(O1)[i];
    float4 b = reinterpret_cast<const float4*>(O2)[i];
    bf16x4 pk;
    pk[0] = (bf16)((a.x + b.x) * inv);
    pk[1] = (bf16)((a.y + b.y) * inv);
    pk[2] = (bf16)((a.z + b.z) * inv);
    pk[3] = (bf16)((a.w + b.w) * inv);
    *reinterpret_cast<bf16x4*>(
        O + ((size_t)(n * S_LEN + qt * QT + row)) * EMB + h * 64 + (i & 15) * 4) = pk;
  }
}

extern "C" void kernel_launch(void* const* d_in, const int* in_sizes, int n_in,
                              void* d_out, int out_size, void* d_ws, size_t ws_size,
                              hipStream_t stream) {
  (void)in_sizes; (void)n_in; (void)out_size; (void)ws_size;
  const float* values = (const float*)d_in[0];
  const float* keys   = (const float*)d_in[1];
  const float* query  = (const float*)d_in[2];
  // d_in[3] = mask: reference takes the causal tril path — unused.
  const float* Wv = (const float*)d_in[4];
  const float* bv = (const float*)d_in[5];
  const float* Wk = (const float*)d_in[6];
  const float* bk = (const float*)d_in[7];
  const float* Wq = (const float*)d_in[8];
  const float* bq = (const float*)d_in[9];
  const float* Wo = (const float*)d_in[10];
  const float* bo = (const float*)d_in[11];
  float* out = (float*)d_out;

  const int E = 1024;
  const int M = 2 * 2048;  // 4096
  const size_t MB_ = 1u << 20;
  char* ws = (char*)d_ws;
  bf16* kh  = (bf16*)(ws + 32 * MB_);  // K per-head [N,H,S,64]
  bf16* qh  = (bf16*)(ws + 40 * MB_);  // Q per-head [N,H,S,64]
  bf16* vt  = (bf16*)(ws + 48 * MB_);  // V per-head transposed [N,H,64,S]
  bf16* ao  = (bf16*)(ws + 56 * MB_);  // attention out, row-major [N,S,E]
  float* Opart = (float*)(ws + 0 * MB_);   // 16 MB
  float* lpart = (float*)(ws + 17 * MB_);  // 256 KB

  gemm_qkv<<<dim3(E / 128, M / 128, 3), 256, 32768, stream>>>(
      query, Wq, bq, qh,
      keys, Wk, bk, kh,
      values, Wv, bv, vt);

  attn_kernel<<<dim3(256, 3), 256, 0, stream>>>(qh, kh, vt, ao, Opart, lpart);
  attn_combine<<<dim3(256), 256, 0, stream>>>(Opart, lpart, ao);

  gemm_out<<<dim3(16, 32), 256, 24576, stream>>>(ao, Wo, bo, out);
}

// Round 14
// 220.791 us; speedup vs baseline: 1.0891x; 1.0891x over previous
//
#include <hip/hip_runtime.h>

typedef __bf16 bf16;
typedef __bf16 bf16x4 __attribute__((ext_vector_type(4)));
typedef __bf16 bf16x8 __attribute__((ext_vector_type(8)));
typedef float floatx4 __attribute__((ext_vector_type(4)));

#define GLOAD_LDS16(gp, lp) \
  __builtin_amdgcn_global_load_lds( \
      (const __attribute__((address_space(1))) void*)(gp), \
      (__attribute__((address_space(3))) void*)(lp), 16, 0, 0)

// ---------------- fused fp32 -> bf16 conversion (all 7 tensors) ----------------
// Standalone pass is CHEAPER than fusing into the GEMMs: R5 (frag-read cvt,
// -50us) and R13 (reg-staged cvt, -28us) both lost vs this + global_load_lds.
__global__ __launch_bounds__(256) void cvt_all_kernel(
    const float* __restrict__ v, const float* __restrict__ k, const float* __restrict__ q,
    const float* __restrict__ wv, const float* __restrict__ wk,
    const float* __restrict__ wq, const float* __restrict__ wo,
    bf16* __restrict__ xv, bf16* __restrict__ xk, bf16* __restrict__ xq,
    bf16* __restrict__ bwv, bf16* __restrict__ bwk, bf16* __restrict__ bwq,
    bf16* __restrict__ bwo) {
  const int i = blockIdx.x * 256 + threadIdx.x;  // float4 index over 4M total
  const int A4 = 1 << 20;
  const float* src; bf16* dst; int off;
  if (i < A4)            { src = v; dst = xv; off = i; }
  else if (i < 2 * A4)   { src = k; dst = xk; off = i - A4; }
  else if (i < 3 * A4)   { src = q; dst = xq; off = i - 2 * A4; }
  else {
    int j = i - 3 * A4; int r = j >> 18; off = j & ((1 << 18) - 1);
    src = (r == 0) ? wv : (r == 1) ? wk : (r == 2) ? wq : wo;
    dst = (r == 0) ? bwv : (r == 1) ? bwk : (r == 2) ? bwq : bwo;
  }
  float4 x = reinterpret_cast<const float4*>(src)[off];
  union { bf16 b[4]; short4 s; } u;
  u.b[0] = (bf16)x.x; u.b[1] = (bf16)x.y; u.b[2] = (bf16)x.z; u.b[3] = (bf16)x.w;
  reinterpret_cast<short4*>(dst)[off] = u.s;
}

// ---------------- bf16 GEMM body (R4-verified): C = A @ B^T + bias ----------------
// Static-indexed full-LDS double buffer; one barrier/step; stage(t+1) issued
// right after the barrier -> drained at the NEXT barrier after a compute phase.
// 2-phase structural floor (~520 TF) confirmed by R2/R4/R12/R13 A/Bs.
// MODE 0: bf16 out, per-head [N,H,S,64] (Q,K). MODE 1: per-head transposed (V).
template <int MODE>
__device__ __forceinline__ void gemm_body(
    const bf16* __restrict__ A, const bf16* __restrict__ B,
    const float* __restrict__ bias, void* __restrict__ Cout,
    int bx, int by, bf16* __restrict__ SMEM) {
  constexpr int K = 1024;
  constexpr int NSTEP = K / 32;  // 32
  const int tid = threadIdx.x;
  const int lane = tid & 63;
  const int wave = tid >> 6;
  const int quad = lane >> 4;
  const int l16 = lane & 15;
  const int wm = (wave >> 1) * 64;
  const int wn = (wave & 1) * 64;
  const int am0 = by * 128;
  const int bn0 = bx * 128;
  const int srow = lane >> 2;
  const int scol = (lane & 3) * 8;

  floatx4 acc[4][4] = {};

  auto stage = [&](int step, int bufsel) {
    const int k0 = step * 32;
    bf16* As = SMEM + bufsel * 8192;
    bf16* Bs = As + 4096;
#pragma unroll
    for (int j = 0; j < 2; j++) {
      const int chunk = wave * 2 + j;
      const int row = chunk * 16 + srow;
      GLOAD_LDS16(A + (size_t)(am0 + row) * K + k0 + scol, As + chunk * 512);
      GLOAD_LDS16(B + (size_t)(bn0 + row) * K + k0 + scol, Bs + chunk * 512);
    }
  };

  auto compute = [&](int bufsel) {
    const bf16* As = SMEM + bufsel * 8192;
    const bf16* Bs = As + 4096;
    bf16x8 af[4], bfv[4];
#pragma unroll
    for (int mi = 0; mi < 4; mi++)
      af[mi] = *reinterpret_cast<const bf16x8*>(&As[(wm + mi * 16 + l16) * 32 + quad * 8]);
#pragma unroll
    for (int ni = 0; ni < 4; ni++)
      bfv[ni] = *reinterpret_cast<const bf16x8*>(&Bs[(wn + ni * 16 + l16) * 32 + quad * 8]);
#pragma unroll
    for (int mi = 0; mi < 4; mi++)
#pragma unroll
      for (int ni = 0; ni < 4; ni++)
        acc[mi][ni] = __builtin_amdgcn_mfma_f32_16x16x32_bf16(af[mi], bfv[ni], acc[mi][ni], 0, 0, 0);
  };

  stage(0, 0);
  for (int t = 0; t < NSTEP; t += 2) {
    __syncthreads();
    stage(t + 1, 1);
    compute(0);                 // step t   -> buf0
    __syncthreads();
    if (t + 2 < NSTEP) stage(t + 2, 0);
    compute(1);                 // step t+1 -> buf1
  }

  // LDS-bounce epilogue: wave-private 4 KB region, XOR-chunk swizzle,
  // coalesced 16B global stores.  [C/D layout col=lane&15, row=quad*4+reg, m89]
  __syncthreads();
  bf16* T = SMEM + wave * 2048;
  const int nb = (am0 + wm) >> 11;
  const int sq0 = (am0 + wm) & 2047;
  const int h = (bn0 + wn) >> 6;
  const int nh = nb * 16 + h;
  const int r8 = lane >> 3, c8 = lane & 7;

  if constexpr (MODE == 0) {
#pragma unroll
    for (int pp = 0; pp < 2; pp++) {
#pragma unroll
      for (int mm = 0; mm < 2; mm++) {
        const int mi = pp * 2 + mm;
#pragma unroll
        for (int ni = 0; ni < 4; ni++) {
          const int d = ni * 16 + l16;
          const float bc = bias[bn0 + wn + d];
#pragma unroll
          for (int r = 0; r < 4; r++) {
            const int s = mm * 16 + quad * 4 + r;
            T[s * 64 + (d & 7) + 8 * ((d >> 3) ^ (s & 7))] = (bf16)(acc[mi][ni][r] + bc);
          }
        }
      }
#pragma unroll
      for (int it = 0; it < 4; it++) {
        const int s = it * 8 + r8;
        bf16x8 vv = *reinterpret_cast<const bf16x8*>(&T[s * 64 + ((c8 ^ r8) * 8)]);
        *reinterpret_cast<bf16x8*>(
            reinterpret_cast<bf16*>(Cout) +
            ((size_t)nh * 2048 + sq0 + pp * 32 + s) * 64 + c8 * 8) = vv;
      }
    }
  } else {  // MODE == 1
#pragma unroll
    for (int pp = 0; pp < 2; pp++) {
#pragma unroll
      for (int nn = 0; nn < 2; nn++) {
        const int ni = pp * 2 + nn;
        const int dp = nn * 16 + l16;
        const float bc = bias[bn0 + wn + pp * 32 + dp];
#pragma unroll
        for (int mi = 0; mi < 4; mi++) {
#pragma unroll
          for (int r = 0; r < 4; r++) {
            const int s = mi * 16 + quad * 4 + r;
            T[dp * 64 + (s & 7) + 8 * ((s >> 3) ^ (dp & 7))] = (bf16)(acc[mi][ni][r] + bc);
          }
        }
      }
#pragma unroll
      for (int it = 0; it < 4; it++) {
        const int dp = it * 8 + r8;
        bf16x8 vv = *reinterpret_cast<const bf16x8*>(&T[dp * 64 + ((c8 ^ r8) * 8)]);
        *reinterpret_cast<bf16x8*>(
            reinterpret_cast<bf16*>(Cout) +
            ((size_t)nh * 64 + pp * 32 + dp) * 2048 + sq0 + c8 * 8) = vv;
      }
    }
  }
}

// QKV: T1 XCD-contiguous remap (R3-verified: FETCH 101.5 -> 29.8 MB).
__global__ __launch_bounds__(256) void gemm_qkv(
    const bf16* __restrict__ A0, const bf16* __restrict__ B0, const float* __restrict__ c0, bf16* __restrict__ C0,
    const bf16* __restrict__ A1, const bf16* __restrict__ B1, const float* __restrict__ c1, bf16* __restrict__ C1,
    const bf16* __restrict__ A2, const bf16* __restrict__ B2, const float* __restrict__ c2, bf16* __restrict__ C2) {
  extern __shared__ __align__(16) bf16 SMEM[];  // 32 KB dynamic
  const int lin = blockIdx.x + (blockIdx.y << 3) + (blockIdx.z << 8);  // 0..767
  const int swz = (lin & 7) * 96 + (lin >> 3);                          // bijective
  const int bz = swz >> 8;
  const int by = (swz >> 3) & 31;
  const int bx = swz & 7;
  if (bz == 0)      gemm_body<0>(A0, B0, c0, C0, bx, by, SMEM);   // Q
  else if (bz == 1) gemm_body<0>(A1, B1, c1, C1, bx, by, SMEM);   // K
  else              gemm_body<1>(A2, B2, c2, C2, bx, by, SMEM);   // V^T
}

// ---------------- final projection: 128x64 tiles -> 512 blocks = 2/CU (R11-verified) ----------------
__global__ __launch_bounds__(256) void gemm_out(
    const bf16* __restrict__ A, const bf16* __restrict__ B,
    const float* __restrict__ bias, float* __restrict__ C) {
  extern __shared__ __align__(16) bf16 SMEM[];  // 24 KB dynamic
  constexpr int K = 1024, N = 1024;
  constexpr int NSTEP = 32;
  const int lin = blockIdx.x + (blockIdx.y << 4);  // x:0..15, y:0..31
  const int swz = (lin & 7) * 64 + (lin >> 3);     // bijective: 512 = 8*64
  const int by = swz >> 4;        // 0..31
  const int bx = swz & 15;        // 0..15
  const int tid = threadIdx.x;
  const int lane = tid & 63;
  const int wave = tid >> 6;
  const int quad = lane >> 4;
  const int l16 = lane & 15;
  const int wm = (wave >> 1) * 64;   // 0 / 64
  const int wn = (wave & 1) * 32;    // 0 / 32
  const int am0 = by * 128;
  const int bn0 = bx * 64;
  const int srow = lane >> 2;
  const int scol = (lane & 3) * 8;

  floatx4 acc[4][2] = {};

  // per buffer: As 128x32 (8KB) | Bs 64x32 (4KB) = 6144 bf16
  auto stage = [&](int step, int bufsel) {
    const int k0 = step * 32;
    bf16* As = SMEM + bufsel * 6144;
    bf16* Bs = As + 4096;
#pragma unroll
    for (int j = 0; j < 2; j++) {  // A: chunks 2w, 2w+1
      const int chunk = wave * 2 + j;
      const int row = chunk * 16 + srow;
      GLOAD_LDS16(A + (size_t)(am0 + row) * K + k0 + scol, As + chunk * 512);
    }
    {  // B: chunk w (64 rows total)
      const int row = wave * 16 + srow;
      GLOAD_LDS16(B + (size_t)(bn0 + row) * K + k0 + scol, Bs + wave * 512);
    }
  };

  auto compute = [&](int bufsel) {
    const bf16* As = SMEM + bufsel * 6144;
    const bf16* Bs = As + 4096;
    bf16x8 af[4], bfv[2];
#pragma unroll
    for (int mi = 0; mi < 4; mi++)
      af[mi] = *reinterpret_cast<const bf16x8*>(&As[(wm + mi * 16 + l16) * 32 + quad * 8]);
#pragma unroll
    for (int ni = 0; ni < 2; ni++)
      bfv[ni] = *reinterpret_cast<const bf16x8*>(&Bs[(wn + ni * 16 + l16) * 32 + quad * 8]);
#pragma unroll
    for (int mi = 0; mi < 4; mi++)
#pragma unroll
      for (int ni = 0; ni < 2; ni++)
        acc[mi][ni] = __builtin_amdgcn_mfma_f32_16x16x32_bf16(af[mi], bfv[ni], acc[mi][ni], 0, 0, 0);
  };

  stage(0, 0);
  for (int t = 0; t < NSTEP; t += 2) {
    __syncthreads();
    stage(t + 1, 1);
    compute(0);
    __syncthreads();
    if (t + 2 < NSTEP) stage(t + 2, 0);
    compute(1);
  }

  // direct fp32 epilogue [m89 C/D layout]
#pragma unroll
  for (int mi = 0; mi < 4; mi++) {
#pragma unroll
    for (int ni = 0; ni < 2; ni++) {
      const int col = bn0 + wn + ni * 16 + l16;
      const float bb = bias[col];
      const int row = am0 + wm + mi * 16 + quad * 4;
#pragma unroll
      for (int r = 0; r < 4; r++)
        C[(size_t)(row + r) * N + col] = acc[mi][ni][r] + bb;
    }
  }
}

// ---------------- causal flash attention: split-K + zero-shuffle PV ----------------
// Zero-shuffle PV (R7/R8-verified): sigma(quad,j)=kc*32+(j>>2)*16+quad*4+(j&3)
// applied to both PV operands makes the A-operand the lane's own P registers
// (union-aliased, zero packing movs). Combine stays a SEPARATE dispatch:
// R10 proved the fused handshake costs ~40 us (device-scope threadfence forces
// per-XCD L2 writeback; partials cross XCDs at HBM-miss latency inline).
#define S_LEN 2048
#define EMB 1024
#define QT 128
#define KTILE 64
#define SCALE2 (0.03125f * 1.44269504f)

__global__ __launch_bounds__(256) void attn_kernel(
    const bf16* __restrict__ Qh, const bf16* __restrict__ Kh,
    const bf16* __restrict__ Vt, bf16* __restrict__ O,
    float* __restrict__ Opart, float* __restrict__ lpart) {
  __shared__ __align__(16) bf16 Ks[2 * KTILE * 64];  // 2 x 8 KB, swizzled cols
  __shared__ __align__(16) bf16 Vs[2 * 64 * KTILE];  // 2 x 8 KB, swizzled cols

  const int tid = threadIdx.x;
  const int lane = tid & 63;
  const int wave = tid >> 6;
  const int quad = lane >> 4;
  const int l16 = lane & 15;
  const int wq = wave * 32;

  const int c = blockIdx.x;       // 0..255
  const int role = blockIdx.y;    // 0..2
  const int nh = c >> 3;
  const int t = c & 7;
  const int n = nh >> 4;
  const int h = nh & 15;
  int qt, kt0, kt1;
  if (role == 0) { qt = t; kt0 = 0; kt1 = 2 * t + 2; }
  else {
    qt = 15 - t;
    const int halfk = qt + 1;
    kt0 = (role == 1) ? 0 : halfk;
    kt1 = (role == 1) ? halfk : 2 * halfk;
  }
  const int q0 = qt * QT;

  // Q B-frags in registers
  bf16x8 aq[2][2];
  {
    const bf16* Qb = Qh + ((size_t)nh * S_LEN + q0 + wq + l16) * 64 + quad * 8;
#pragma unroll
    for (int mi = 0; mi < 2; mi++)
#pragma unroll
      for (int kc = 0; kc < 2; kc++)
        aq[mi][kc] = *reinterpret_cast<const bf16x8*>(Qb + mi * 16 * 64 + kc * 32);
  }

  float l_part[2] = {};
  floatx4 o_acc[2][4] = {};

  const bf16* Kbase = Kh + (size_t)nh * S_LEN * 64;
  const bf16* Vbase = Vt + (size_t)nh * 64 * S_LEN;

  const int srl = lane >> 3;
  const int sc8 = lane & 7;

  auto stage = [&](int kt) {
    const int k0s = kt * KTILE;
    const int buf = (kt & 1) * 4096;
#pragma unroll
    for (int j = 0; j < 2; j++) {
      const int rl = wave * 16 + j * 8 + srl;
      const int c8s = ((sc8 ^ (rl & 7)) * 8);
      GLOAD_LDS16(Kbase + (size_t)(k0s + rl) * 64 + c8s, Ks + buf + (wave * 16 + j * 8) * 64);
      GLOAD_LDS16(Vbase + (size_t)rl * S_LEN + k0s + c8s, Vs + buf + (wave * 16 + j * 8) * 64);
    }
  };

  stage(kt0);
  for (int kt = kt0; kt < kt1; kt++) {
    const int k0 = kt * KTILE;
    __syncthreads();                  // drains cur-tile staging / buf reuse
    if (kt + 1 < kt1) stage(kt + 1);  // in flight during this tile's compute
    const bf16* Kc = Ks + (kt & 1) * 4096;
    const bf16* Vc = Vs + (kt & 1) * 4096;

    // S^T = K Q^T : col=l16=q, row=quad*4+r=k-pos [m89 layout]
    floatx4 s_acc[2][4] = {};
#pragma unroll
    for (int kc = 0; kc < 2; kc++) {
      bf16x8 bk[4];
#pragma unroll
      for (int ni = 0; ni < 4; ni++)
        bk[ni] = *reinterpret_cast<const bf16x8*>(
            &Kc[(ni * 16 + l16) * 64 + (((kc * 4 + quad) ^ (l16 & 7)) * 8)]);
#pragma unroll
      for (int mi = 0; mi < 2; mi++)
#pragma unroll
        for (int ni = 0; ni < 4; ni++)
          s_acc[mi][ni] = __builtin_amdgcn_mfma_f32_16x16x32_bf16(bk[ni], aq[mi][kc], s_acc[mi][ni], 0, 0, 0);
    }

    // max-free exp2 softmax; P in registers; union q[ni]-writes / w[kc]-reads
    const bool needMask = (k0 + KTILE - 1) > (q0 + wq);  // wave-uniform
    const int qg = q0 + wq + l16;
    union PU { bf16x8 w[2]; bf16x4 q[4]; };
    PU P[2];
#pragma unroll
    for (int mi = 0; mi < 2; mi++) {
#pragma unroll
      for (int ni = 0; ni < 4; ni++) {
        const int kgb = k0 + ni * 16 + quad * 4;
        bf16x4 pk;
#pragma unroll
        for (int r = 0; r < 4; r++) {
          float pr = __builtin_amdgcn_exp2f(s_acc[mi][ni][r] * SCALE2);
          if (needMask) pr = ((kgb + r) <= (qg + mi * 16)) ? pr : 0.f;
          l_part[mi] += pr;
          pk[r] = (bf16)pr;
        }
        P[mi].q[ni] = pk;
      }
    }

    // O += P @ V, k-slot bijection sigma: A-operand = P[mi].w[kc]
#pragma unroll
    for (int kc = 0; kc < 2; kc++) {
      bf16x8 bv[4];
#pragma unroll
      for (int di = 0; di < 4; di++) {
        const bf16* base = Vc + (di * 16 + l16) * 64;
        const int e = l16 & 7;
        union VU { bf16x8 v8; bf16x4 h[2]; } vu;
        vu.h[0] = *reinterpret_cast<const bf16x4*>(
            base + (((kc * 4 + (quad >> 1)) ^ e) * 8) + (quad & 1) * 4);
        vu.h[1] = *reinterpret_cast<const bf16x4*>(
            base + (((kc * 4 + 2 + (quad >> 1)) ^ e) * 8) + (quad & 1) * 4);
        bv[di] = vu.v8;
      }
#pragma unroll
      for (int mi = 0; mi < 2; mi++)
#pragma unroll
        for (int di = 0; di < 4; di++)
          o_acc[mi][di] = __builtin_amdgcn_mfma_f32_16x16x32_bf16(P[mi].w[kc], bv[di], o_acc[mi][di], 0, 0, 0);
    }
  }

  // l reduction: sum across the 4 quads (lanes sharing l16)
  float l_sum[2];
#pragma unroll
  for (int mi = 0; mi < 2; mi++) {
    float s = l_part[mi];
    s += __shfl_xor(s, 16);
    s += __shfl_xor(s, 32);
    l_sum[mi] = s;
  }

  if (role == 0) {
    bf16* Op = O + ((size_t)(n * S_LEN + q0 + wq)) * EMB + h * 64;
#pragma unroll
    for (int mi = 0; mi < 2; mi++) {
      const float linv = 1.0f / l_sum[mi];
#pragma unroll
      for (int r = 0; r < 4; r++) {
        const float inv = __shfl(linv, quad * 4 + r);
        bf16* orow = Op + (size_t)(mi * 16 + quad * 4 + r) * EMB;
#pragma unroll
        for (int di = 0; di < 4; di++)
          orow[di * 16 + l16] = (bf16)(o_acc[mi][di][r] * inv);
      }
    }
  } else {
    // half chunk: store fp32 partials (slot = c, chunk = role-1)
    float* Ob = Opart + ((size_t)c * 2 + (role - 1)) * (QT * 64);
    float* lb = lpart + ((size_t)c * 2 + (role - 1)) * QT;
#pragma unroll
    for (int mi = 0; mi < 2; mi++)
      if (lane < 16) lb[wq + mi * 16 + lane] = l_sum[mi];
#pragma unroll
    for (int mi = 0; mi < 2; mi++)
#pragma unroll
      for (int r = 0; r < 4; r++) {
        float* orow = Ob + (size_t)(wq + mi * 16 + quad * 4 + r) * 64;
#pragma unroll
        for (int di = 0; di < 4; di++)
          orow[di * 16 + l16] = o_acc[mi][di][r];
      }
  }
}

// ---------------- combine: O = (O1+O2)/(l1+l2) for qt = 8..15 ----------------
__global__ __launch_bounds__(256) void attn_combine(
    const float* __restrict__ Opart, const float* __restrict__ lpart,
    bf16* __restrict__ O) {
  const int c = blockIdx.x;            // 0..255
  const int nh = c >> 3;
  const int t = c & 7;
  const int qt = 15 - t;
  const int n = nh >> 4;
  const int h = nh & 15;
  const float* O1 = Opart + (size_t)c * 2 * (QT * 64);
  const float* O2 = O1 + QT * 64;
  const float* l1 = lpart + (size_t)c * 2 * QT;
  const float* l2 = l1 + QT;
  const int tid = threadIdx.x;
  for (int i = tid; i < QT * 64 / 4; i += 256) {  // float4 granularity
    const int row = i >> 4;
    const float inv = 1.0f / (l1[row] + l2[row]);
    float4 a = reinterpret_cast<const float4*>(O1)[i];
    float4 b = reinterpret_cast<const float4*>(O2)[i];
    bf16x4 pk;
    pk[0] = (bf16)((a.x + b.x) * inv);
    pk[1] = (bf16)((a.y + b.y) * inv);
    pk[2] = (bf16)((a.z + b.z) * inv);
    pk[3] = (bf16)((a.w + b.w) * inv);
    *reinterpret_cast<bf16x4*>(
        O + ((size_t)(n * S_LEN + qt * QT + row)) * EMB + h * 64 + (i & 15) * 4) = pk;
  }
}

extern "C" void kernel_launch(void* const* d_in, const int* in_sizes, int n_in,
                              void* d_out, int out_size, void* d_ws, size_t ws_size,
                              hipStream_t stream) {
  (void)in_sizes; (void)n_in; (void)out_size; (void)ws_size;
  const float* values = (const float*)d_in[0];
  const float* keys   = (const float*)d_in[1];
  const float* query  = (const float*)d_in[2];
  // d_in[3] = mask: reference takes the causal tril path — unused.
  const float* Wv = (const float*)d_in[4];
  const float* bv = (const float*)d_in[5];
  const float* Wk = (const float*)d_in[6];
  const float* bk = (const float*)d_in[7];
  const float* Wq = (const float*)d_in[8];
  const float* bq = (const float*)d_in[9];
  const float* Wo = (const float*)d_in[10];
  const float* bo = (const float*)d_in[11];
  float* out = (float*)d_out;

  const int S = 2048, E = 1024;
  const int M = 2 * S;  // 4096
  const size_t MB_ = 1u << 20;
  char* ws = (char*)d_ws;
  bf16* xv  = (bf16*)(ws + 0 * MB_);   // dead after gemm_qkv
  bf16* xk  = (bf16*)(ws + 8 * MB_);   // dead after gemm_qkv
  bf16* xq  = (bf16*)(ws + 16 * MB_);  // dead after gemm_qkv
  bf16* wvb = (bf16*)(ws + 24 * MB_);
  bf16* wkb = (bf16*)(ws + 26 * MB_);
  bf16* wqb = (bf16*)(ws + 28 * MB_);
  bf16* wob = (bf16*)(ws + 30 * MB_);
  bf16* kh  = (bf16*)(ws + 32 * MB_);  // K per-head [N,H,S,64]
  bf16* qh  = (bf16*)(ws + 40 * MB_);  // Q per-head [N,H,S,64]
  bf16* vt  = (bf16*)(ws + 48 * MB_);  // V per-head transposed [N,H,64,S]
  bf16* ao  = (bf16*)(ws + 56 * MB_);  // attention out, row-major [N,S,E]
  // fp32 partials overlay the dead xv/xk/xq region (written after gemm_qkv reads)
  float* Opart = (float*)(ws + 0 * MB_);   // 16 MB
  float* lpart = (float*)(ws + 17 * MB_);  // 256 KB

  cvt_all_kernel<<<(4 << 20) / 256, 256, 0, stream>>>(
      values, keys, query, Wv, Wk, Wq, Wo,
      xv, xk, xq, wvb, wkb, wqb, wob);

  gemm_qkv<<<dim3(E / 128, M / 128, 3), 256, 32768, stream>>>(
      xq, wqb, bq, qh,
      xk, wkb, bk, kh,
      xv, wvb, bv, vt);

  attn_kernel<<<dim3(256, 3), 256, 0, stream>>>(qh, kh, vt, ao, Opart, lpart);
  attn_combine<<<dim3(256), 256, 0, stream>>>(Opart, lpart, ao);

  gemm_out<<<dim3(16, 32), 256, 24576, stream>>>(ao, wob, bo, out);
}